// Round 12
// baseline (319.740 us; speedup 1.0000x reference)
//
#include <hip/hip_runtime.h>

#define E_      8
#define D_      1024
#define H_      2048
#define TOKENS  8192
#define RROWS   16384            // routed rows total (= TOKENS * TOP_K), exact
#define HPAD_ROWS (RROWS + 256)  // pad so GEMM2 A-staging over-read stays in bounds

using bf16x8 = __attribute__((ext_vector_type(8))) __bf16;
using f32x4  = __attribute__((ext_vector_type(4))) float;

__device__ __forceinline__ unsigned short f2bf(float f) {
  unsigned u = __builtin_bit_cast(unsigned, f);
  u += 0x7fffu + ((u >> 16) & 1u);   // RNE
  return (unsigned short)(u >> 16);
}
__device__ __forceinline__ float bf2f(unsigned short u) {
  unsigned v = (unsigned)u << 16;
  return __builtin_bit_cast(float, v);
}

// async global->LDS, 16B per lane; LDS dest is wave-uniform base + lane*16
#define GLDS16(g, l) __builtin_amdgcn_global_load_lds( \
    (const __attribute__((address_space(1))) unsigned int*)(g), \
    (__attribute__((address_space(3))) unsigned int*)(l), 16, 0, 0)

#define SBAR() asm volatile("s_barrier" ::: "memory")
#define LGKM0() do { asm volatile("s_waitcnt lgkmcnt(0)" ::: "memory"); \
                     __builtin_amdgcn_sched_barrier(0); } while (0)
#define VMC(N) asm volatile("s_waitcnt vmcnt(" #N ")" ::: "memory")

// ---------------- fused prologue (unchanged r11) ----------------

__global__ void prologue_kernel(const float* __restrict__ x, const float* __restrict__ gate,
                                unsigned short* __restrict__ xb,
                                int* __restrict__ sel, float* __restrict__ wsel,
                                const float* __restrict__ W1, unsigned short* __restrict__ w1t,
                                const float* __restrict__ W2, unsigned short* __restrict__ w2t) {
  __shared__ float tile[64][65];
  int b = blockIdx.x;
  const int NG = TOKENS / 4;
  if (b < NG) {
    int lane = threadIdx.x & 63, wid = threadIdx.x >> 6;
    int t = (b << 2) + wid;
    const float* xr = x + (size_t)t * D_;
    unsigned short* xbr = xb + (size_t)t * D_;
    float acc[8];
#pragma unroll
    for (int e = 0; e < 8; e++) acc[e] = 0.f;
#pragma unroll
    for (int i = 0; i < 4; i++) {
      int d0 = (i << 8) + (lane << 2);
      float4 xv = *reinterpret_cast<const float4*>(xr + d0);
      ushort4 o = make_ushort4(f2bf(xv.x), f2bf(xv.y), f2bf(xv.z), f2bf(xv.w));
      *reinterpret_cast<ushort4*>(xbr + d0) = o;
      float xa[4] = {xv.x, xv.y, xv.z, xv.w};
#pragma unroll
      for (int j = 0; j < 4; j++) {
        const float4* g4 = reinterpret_cast<const float4*>(gate + (size_t)(d0 + j) * 8);
        float4 ga = g4[0], gb = g4[1];
        acc[0] += xa[j] * ga.x; acc[1] += xa[j] * ga.y;
        acc[2] += xa[j] * ga.z; acc[3] += xa[j] * ga.w;
        acc[4] += xa[j] * gb.x; acc[5] += xa[j] * gb.y;
        acc[6] += xa[j] * gb.z; acc[7] += xa[j] * gb.w;
      }
    }
#pragma unroll
    for (int e = 0; e < 8; e++) {
#pragma unroll
      for (int off = 32; off; off >>= 1) acc[e] += __shfl_xor(acc[e], off);
    }
    if (lane == 0) {
      int i0 = 0; float v0 = acc[0];
#pragma unroll
      for (int e = 1; e < 8; e++) if (acc[e] > v0) { v0 = acc[e]; i0 = e; }
      int i1 = -1; float v1 = -3.4e38f;
#pragma unroll
      for (int e = 0; e < 8; e++) if (e != i0 && acc[e] > v1) { v1 = acc[e]; i1 = e; }
      float p1 = expf(v1 - v0);
      float inv = 1.f / (1.f + p1);
      sel[t * 2] = i0; sel[t * 2 + 1] = i1;
      wsel[t * 2] = inv; wsel[t * 2 + 1] = p1 * inv;
    }
    return;
  }
  b -= NG;
  const int nb1 = E_ * (D_ >> 6) * (H_ >> 6);
  const float* src; unsigned short* dst; int R, C;
  if (b < nb1) { src = W1; dst = w1t; R = D_; C = H_; }
  else         { src = W2; dst = w2t; R = H_; C = D_; b -= nb1; }
  int tilesC = C >> 6;
  int per = (R >> 6) * tilesC;
  int e = b / per, rem = b % per;
  int rb = rem / tilesC, cb = rem % tilesC;
  const float* s = src + (size_t)e * R * C;
  unsigned short* d = dst + (size_t)e * R * C;
  int r0 = rb << 6, c0 = cb << 6;
#pragma unroll
  for (int i = 0; i < 16; i++) {
    int idx = threadIdx.x + i * 256;
    int lr = idx >> 6, lc = idx & 63;
    tile[lr][lc] = s[(size_t)(r0 + lr) * C + (c0 + lc)];
  }
  __syncthreads();
#pragma unroll
  for (int i = 0; i < 16; i++) {
    int idx = threadIdx.x + i * 256;
    int lr = idx >> 6, lc = idx & 63;
    d[(size_t)(c0 + lr) * R + (r0 + lc)] = f2bf(tile[lc][lr]);
  }
}

// Deterministic atomic-free routing (unchanged r11)
__global__ __launch_bounds__(1024) void route_kernel(
    const int* __restrict__ sel, int* __restrict__ cnt, int* __restrict__ off,
    int* __restrict__ tok_id, int* __restrict__ pos) {
  const int tid = threadIdx.x;
  const int lane = tid & 63, wid = tid >> 6;
  __shared__ int wtot[16][8];
  __shared__ int woff[16][8];
  __shared__ int offs[8];
  int sv[16];
  const int s0 = tid << 4;
#pragma unroll
  for (int q = 0; q < 4; q++) {
    int4 v = reinterpret_cast<const int4*>(sel + s0)[q];
    sv[q * 4 + 0] = v.x; sv[q * 4 + 1] = v.y;
    sv[q * 4 + 2] = v.z; sv[q * 4 + 3] = v.w;
  }
  int h[8];
#pragma unroll
  for (int e = 0; e < 8; e++) h[e] = 0;
#pragma unroll
  for (int j = 0; j < 16; j++) {
    int ev = sv[j];
#pragma unroll
    for (int e = 0; e < 8; e++) h[e] += (ev == e) ? 1 : 0;
  }
  int excl[8];
#pragma unroll
  for (int e = 0; e < 8; e++) {
    int v = h[e];
#pragma unroll
    for (int d = 1; d < 64; d <<= 1) {
      int u = __shfl_up(v, d);
      if (lane >= d) v += u;
    }
    excl[e] = v - h[e];
    if (lane == 63) wtot[wid][e] = v;
  }
  __syncthreads();
  if (tid == 0) {
    int run[8];
#pragma unroll
    for (int e = 0; e < 8; e++) run[e] = 0;
    for (int w = 0; w < 16; w++)
#pragma unroll
      for (int e = 0; e < 8; e++) { woff[w][e] = run[e]; run[e] += wtot[w][e]; }
    int a = 0;
    for (int e = 0; e < 8; e++) { offs[e] = a; off[e] = a; cnt[e] = run[e]; a += run[e]; }
  }
  __syncthreads();
  int base[8];
#pragma unroll
  for (int e = 0; e < 8; e++) base[e] = offs[e] + woff[wid][e] + excl[e];
#pragma unroll
  for (int j = 0; j < 16; j++) {
    int ev = sv[j];
    int p = 0;
#pragma unroll
    for (int e = 0; e < 8; e++) if (ev == e) { p = base[e]; base[e] = p + 1; }
    pos[s0 + j] = p;
    tok_id[p] = (s0 + j) >> 1;
  }
}

// ---------------- grouped GEMMs: 256x256 8-phase counted-vmcnt (m201 port) ----------------
// 8 waves (2M x 4N), wave output 128x64, acc[8][4]. BK=64.
// LDS per operand: [2 slot][2 half][128 rows][64 k] bf16 = 64 KB; A+B = 128 KB.
// Half-tile = 16 KB = 512 thr x 2 GLDS16. Swizzle: chunk16 ^= (row&7) on the
// per-lane GLOBAL source, LDS linear (r6-proven, 0 conflicts).
// Per iteration (tiles u even, u+1): 8 phases; stage P1..P8 =
// A1(u+1),B1(u+1),B0(u+2),A0(u+2),A1(u+2),B1(u+2),B0(u+3),A0(u+3) — each
// half staged exactly one phase after its last reader (A-halves read P1&P3 /
// P5&P7 by wr-waves; B-halves P1&P2 / P5&P6 by wc-waves). vmcnt(4) at P4,P8
// certifies the next tile's 4 halves landed (oldest-8-of-12 accounting);
// barrier after vmcnt makes per-wave certification global. Last iteration
// peeled: stages only P1,P2; vmcnt(0) at P4.

// stage macros (names resolve in kernel scope)
#define STA(t, h) do { \
    char* d_ = ASMc + (((t) & 1) << 15) + ((h) << 14) + (wid << 10); \
    GLDS16(Ab + gA[(h)*2+0] + ((size_t)(t) << 7), d_); \
    GLDS16(Ab + gA[(h)*2+1] + ((size_t)(t) << 7), d_ + 8192); \
  } while (0)
#define STB(t, h) do { \
    char* d_ = BSMc + (((t) & 1) << 15) + ((h) << 14) + (wid << 10); \
    GLDS16(Bb + gB[(h)*2+0] + ((size_t)(t) << 7), d_); \
    GLDS16(Bb + gB[(h)*2+1] + ((size_t)(t) << 7), d_ + 8192); \
  } while (0)
// frag reads: a[m][kk] for m-half mh from slot s; b[nh*2+n][kk]
#define RDA(mh, s) do { const char* Ap_ = ASMc + ((s) << 15) + aRd + ((mh) << 13); \
  _Pragma("unroll") for (int m_ = 0; m_ < 4; m_++) { \
    a[m_][0] = *(const bf16x8*)(Ap_ + m_ * 2048 + cby0); \
    a[m_][1] = *(const bf16x8*)(Ap_ + m_ * 2048 + cby1); } } while (0)
#define RDB(nh, s) do { const char* Bp_ = BSMc + ((s) << 15) + bRd + ((nh) << 12); \
  _Pragma("unroll") for (int n_ = 0; n_ < 2; n_++) { \
    b[(nh)*2+n_][0] = *(const bf16x8*)(Bp_ + n_ * 2048 + cby0); \
    b[(nh)*2+n_][1] = *(const bf16x8*)(Bp_ + n_ * 2048 + cby1); } } while (0)
// 16 MFMA: m-block mb (0 or 4) x n-half nh
#define MF(mb, nh) do { \
  __builtin_amdgcn_s_setprio(1); \
  _Pragma("unroll") for (int m_ = 0; m_ < 4; m_++) \
    _Pragma("unroll") for (int nl_ = 0; nl_ < 2; nl_++) { \
      const int n_ = (nh)*2 + nl_; \
      acc[(mb)+m_][n_] = __builtin_amdgcn_mfma_f32_16x16x32_bf16(a[m_][0], b[n_][0], acc[(mb)+m_][n_], 0, 0, 0); \
      acc[(mb)+m_][n_] = __builtin_amdgcn_mfma_f32_16x16x32_bf16(a[m_][1], b[n_][1], acc[(mb)+m_][n_], 0, 0, 0); \
    } \
  __builtin_amdgcn_s_setprio(0); \
} while (0)

__global__ __launch_bounds__(512, 2) void gemm1_kernel(
    const unsigned short* __restrict__ xb,    // [TOKENS][D_] bf16
    const unsigned short* __restrict__ w1t,   // [E][H][D] bf16 (k=d contiguous)
    const float* __restrict__ b1,             // [E][H]
    unsigned short* __restrict__ hbuf,        // [HPAD_ROWS][H_] bf16
    const int* __restrict__ tok_id,
    const int* __restrict__ cnt, const int* __restrict__ off) {
  const int nwg = E_ * 16 * 8;               // 1024; 128/expert -> XCD-chunked
  const int raw = blockIdx.x;
  const int bid = (raw & 7) * (nwg >> 3) + (raw >> 3);
  const int e  = bid >> 7;
  const int rb = (bid >> 3) & 15;
  const int cb = bid & 7;
  const int rows = cnt[e];
  const int m0 = rb << 8;                    // BM=256
  if (m0 >= rows) return;
  const int base = off[e];
  const int tid = threadIdx.x, lane = tid & 63, wid = tid >> 6;
  const int wr = wid >> 2, wc = wid & 3;

  __shared__ __align__(16) unsigned short Asm[2 * 2 * 128 * 64];
  __shared__ __align__(16) unsigned short Bsm[2 * 2 * 128 * 64];
  char* ASMc = (char*)Asm;
  char* BSMc = (char*)Bsm;

  const unsigned swzb = (unsigned)(((tid & 7) ^ ((tid >> 3) & 7)) << 4);
  const int n0 = cb << 8;
  unsigned gA[4], gB[4];
#pragma unroll
  for (int h = 0; h < 2; h++)
#pragma unroll
    for (int L = 0; L < 2; L++) {
      int r = h * 128 + L * 64 + (tid >> 3);
      int ar = m0 + r; if (ar >= rows) ar = rows - 1;   // clamp (never stored)
      gA[h*2+L] = (unsigned)tok_id[base + ar] * (D_ * 2) + swzb;
      gB[h*2+L] = (unsigned)(n0 + r) * (D_ * 2) + swzb;
    }
  const char* Ab = (const char*)xb;
  const char* Bb = (const char*)w1t + (size_t)e * H_ * D_ * 2;

  const int aRd = (wr << 14) + (lane & 15) * 128;
  const int bRd = ((wc >> 1) << 14) + (((wc & 1) << 6) + (lane & 15)) * 128;
  const int cby0 = ((lane >> 4) ^ (lane & 7)) << 4;
  const int cby1 = ((4 + (lane >> 4)) ^ (lane & 7)) << 4;

  f32x4 acc[8][4] = {};
  bf16x8 a[4][2], b[4][2];
  const int NIT = (D_ / 64) / 2;             // 8

  // prologue: tile0 fully + tile1 A0,B0 (12 loads/thread)
  STA(0, 0); STA(0, 1); STB(0, 0); STB(0, 1);
  STA(1, 0); STB(1, 0);
  VMC(4); SBAR();

  for (int it = 0; it < NIT - 1; ++it) {
    const int u = it * 2;
    // P1
    RDA(0, 0); RDB(0, 0); STA(u + 1, 1);
    SBAR(); LGKM0(); MF(0, 0); SBAR();
    // P2
    RDB(1, 0); STB(u + 1, 1);
    SBAR(); LGKM0(); MF(0, 1); SBAR();
    // P3
    RDA(1, 0); STB(u + 2, 0);
    SBAR(); LGKM0(); MF(4, 0); SBAR();
    // P4
    STA(u + 2, 0);
    SBAR(); MF(4, 1); VMC(4); SBAR();
    // P5
    RDA(0, 1); RDB(0, 1); STA(u + 2, 1);
    SBAR(); LGKM0(); MF(0, 0); SBAR();
    // P6
    RDB(1, 1); STB(u + 2, 1);
    SBAR(); LGKM0(); MF(0, 1); SBAR();
    // P7
    RDA(1, 1); STB(u + 3, 0);
    SBAR(); LGKM0(); MF(4, 0); SBAR();
    // P8
    STA(u + 3, 0);
    SBAR(); MF(4, 1); VMC(4); SBAR();
  }
  {   // peeled last iteration: u = 2*(NIT-1)
    const int u = (NIT - 1) * 2;
    RDA(0, 0); RDB(0, 0); STA(u + 1, 1);
    SBAR(); LGKM0(); MF(0, 0); SBAR();
    RDB(1, 0); STB(u + 1, 1);
    SBAR(); LGKM0(); MF(0, 1); SBAR();
    RDA(1, 0);
    SBAR(); LGKM0(); MF(4, 0); SBAR();
    SBAR(); MF(4, 1); VMC(0); SBAR();
    RDA(0, 1); RDB(0, 1);
    SBAR(); LGKM0(); MF(0, 0); SBAR();
    RDB(1, 1);
    SBAR(); LGKM0(); MF(0, 1); SBAR();
    RDA(1, 1);
    SBAR(); LGKM0(); MF(4, 0); SBAR();
    SBAR(); MF(4, 1); SBAR();
  }

  const int rcnt = rows - m0;
  const float* b1e = b1 + e * H_;
#pragma unroll
  for (int m = 0; m < 8; m++) {
#pragma unroll
    for (int q = 0; q < 4; q++) {
      int rl = (wr << 7) + (m << 4) + ((lane >> 4) << 2) + q;
      if (rl < rcnt) {
        unsigned short* hrow = hbuf + (size_t)(base + m0 + rl) * H_;
#pragma unroll
        for (int n = 0; n < 4; n++) {
          int ncol = n0 + (wc << 6) + (n << 4) + (lane & 15);
          float v = acc[m][n][q] + b1e[ncol];
          hrow[ncol] = f2bf(fmaxf(v, 0.f));
        }
      }
    }
  }
}

__global__ __launch_bounds__(512, 2) void gemm2_kernel(
    const unsigned short* __restrict__ hbuf,  // [HPAD_ROWS][H_] bf16
    const unsigned short* __restrict__ w2t,   // [E][D][H] bf16 (k=h contiguous)
    unsigned short* __restrict__ eout,        // [RROWS][D_] bf16 (per-slot y)
    const int* __restrict__ cnt, const int* __restrict__ off) {
  const int nwg = E_ * 16 * 4;               // 512; 64/expert -> XCD-chunked
  const int raw = blockIdx.x;
  const int bid = (raw & 7) * (nwg >> 3) + (raw >> 3);
  const int e  = bid >> 6;
  const int rb = (bid >> 2) & 15;
  const int cb = bid & 3;
  const int rows = cnt[e];
  const int m0 = rb << 8;
  if (m0 >= rows) return;
  const int base = off[e];
  const int tid = threadIdx.x, lane = tid & 63, wid = tid >> 6;
  const int wr = wid >> 2, wc = wid & 3;

  __shared__ __align__(16) unsigned short Asm[2 * 2 * 128 * 64];
  __shared__ __align__(16) unsigned short Bsm[2 * 2 * 128 * 64];
  char* ASMc = (char*)Asm;
  char* BSMc = (char*)Bsm;

  const unsigned swzb = (unsigned)(((tid & 7) ^ ((tid >> 3) & 7)) << 4);
  const int n0 = cb << 8;
  unsigned gA[4], gB[4];
#pragma unroll
  for (int h = 0; h < 2; h++)
#pragma unroll
    for (int L = 0; L < 2; L++) {
      int r = h * 128 + L * 64 + (tid >> 3);
      gA[h*2+L] = (unsigned)((size_t)(base + m0 + r) * (H_ * 2)) + swzb;  // pad-safe
      gB[h*2+L] = (unsigned)(n0 + r) * (H_ * 2) + swzb;
    }
  const char* Ab = (const char*)hbuf;
  const char* Bb = (const char*)w2t + (size_t)e * D_ * H_ * 2;

  const int aRd = (wr << 14) + (lane & 15) * 128;
  const int bRd = ((wc >> 1) << 14) + (((wc & 1) << 6) + (lane & 15)) * 128;
  const int cby0 = ((lane >> 4) ^ (lane & 7)) << 4;
  const int cby1 = ((4 + (lane >> 4)) ^ (lane & 7)) << 4;

  f32x4 acc[8][4] = {};
  bf16x8 a[4][2], b[4][2];
  const int NIT = (H_ / 64) / 2;             // 16

  STA(0, 0); STA(0, 1); STB(0, 0); STB(0, 1);
  STA(1, 0); STB(1, 0);
  VMC(4); SBAR();

  for (int it = 0; it < NIT - 1; ++it) {
    const int u = it * 2;
    RDA(0, 0); RDB(0, 0); STA(u + 1, 1);
    SBAR(); LGKM0(); MF(0, 0); SBAR();
    RDB(1, 0); STB(u + 1, 1);
    SBAR(); LGKM0(); MF(0, 1); SBAR();
    RDA(1, 0); STB(u + 2, 0);
    SBAR(); LGKM0(); MF(4, 0); SBAR();
    STA(u + 2, 0);
    SBAR(); MF(4, 1); VMC(4); SBAR();
    RDA(0, 1); RDB(0, 1); STA(u + 2, 1);
    SBAR(); LGKM0(); MF(0, 0); SBAR();
    RDB(1, 1); STB(u + 2, 1);
    SBAR(); LGKM0(); MF(0, 1); SBAR();
    RDA(1, 1); STB(u + 3, 0);
    SBAR(); LGKM0(); MF(4, 0); SBAR();
    STA(u + 3, 0);
    SBAR(); MF(4, 1); VMC(4); SBAR();
  }
  {
    const int u = (NIT - 1) * 2;
    RDA(0, 0); RDB(0, 0); STA(u + 1, 1);
    SBAR(); LGKM0(); MF(0, 0); SBAR();
    RDB(1, 0); STB(u + 1, 1);
    SBAR(); LGKM0(); MF(0, 1); SBAR();
    RDA(1, 0);
    SBAR(); LGKM0(); MF(4, 0); SBAR();
    SBAR(); MF(4, 1); VMC(0); SBAR();
    RDA(0, 1); RDB(0, 1);
    SBAR(); LGKM0(); MF(0, 0); SBAR();
    RDB(1, 1);
    SBAR(); LGKM0(); MF(0, 1); SBAR();
    RDA(1, 1);
    SBAR(); LGKM0(); MF(4, 0); SBAR();
    SBAR(); MF(4, 1); SBAR();
  }

  const int rcnt = rows - m0;
#pragma unroll
  for (int m = 0; m < 8; m++) {
#pragma unroll
    for (int q = 0; q < 4; q++) {
      int rl = (wr << 7) + (m << 4) + ((lane >> 4) << 2) + q;
      if (rl < rcnt) {
        unsigned short* erow = eout + (size_t)(base + m0 + rl) * D_;
#pragma unroll
        for (int n = 0; n < 4; n++) {
          int ncol = n0 + (wc << 6) + (n << 4) + (lane & 15);
          erow[ncol] = f2bf(acc[m][n][q]);
        }
      }
    }
  }
}

// out[t] = w0*(eout[p0] + b2[e0]) + w1*(eout[p1] + b2[e1]); 4 tokens/block
__global__ void combine_kernel(const unsigned short* __restrict__ eout,
                               const float* __restrict__ b2,
                               const int* __restrict__ sel, const float* __restrict__ wsel,
                               const int* __restrict__ pos,
                               float* __restrict__ out) {
  int t = (blockIdx.x << 2) + (threadIdx.x >> 6);
  int lane = threadIdx.x & 63;
  int e0 = sel[t * 2], e1 = sel[t * 2 + 1];
  float w0 = wsel[t * 2], w1 = wsel[t * 2 + 1];
  int p0 = pos[t * 2], p1 = pos[t * 2 + 1];
  const unsigned short* y0r = eout + (size_t)p0 * D_;
  const unsigned short* y1r = eout + (size_t)p1 * D_;
  const float* c0r = b2 + (size_t)e0 * D_;
  const float* c1r = b2 + (size_t)e1 * D_;
  float* orow = out + (size_t)t * D_;
#pragma unroll
  for (int j = 0; j < 4; j++) {
    int d = (j << 8) + (lane << 2);
    ushort4 y0 = *reinterpret_cast<const ushort4*>(y0r + d);
    ushort4 y1 = *reinterpret_cast<const ushort4*>(y1r + d);
    float4 c0 = *reinterpret_cast<const float4*>(c0r + d);
    float4 c1 = *reinterpret_cast<const float4*>(c1r + d);
    float4 o;
    o.x = w0 * (bf2f(y0.x) + c0.x) + w1 * (bf2f(y1.x) + c1.x);
    o.y = w0 * (bf2f(y0.y) + c0.y) + w1 * (bf2f(y1.y) + c1.y);
    o.z = w0 * (bf2f(y0.z) + c0.z) + w1 * (bf2f(y1.z) + c1.z);
    o.w = w0 * (bf2f(y0.w) + c0.w) + w1 * (bf2f(y1.w) + c1.w);
    *reinterpret_cast<float4*>(orow + d) = o;
  }
}

// ---------------- launcher ----------------

extern "C" void kernel_launch(void* const* d_in, const int* in_sizes, int n_in,
                              void* d_out, int out_size, void* d_ws, size_t ws_size,
                              hipStream_t stream) {
  (void)in_sizes; (void)n_in; (void)ws_size; (void)out_size;
  const float* x    = (const float*)d_in[0];
  const float* gate = (const float*)d_in[1];
  const float* W1   = (const float*)d_in[2];
  const float* b1   = (const float*)d_in[3];
  const float* W2   = (const float*)d_in[4];
  const float* b2   = (const float*)d_in[5];
  float* out = (float*)d_out;

  char* p = (char*)d_ws;
  unsigned short* xb   = (unsigned short*)p; p += (size_t)TOKENS * D_ * 2;
  unsigned short* w1t  = (unsigned short*)p; p += (size_t)E_ * H_ * D_ * 2;
  unsigned short* w2t  = (unsigned short*)p; p += (size_t)E_ * D_ * H_ * 2;
  unsigned short* hbuf = (unsigned short*)p; p += (size_t)HPAD_ROWS * H_ * 2;
  int*   tok  = (int*)p;   p += (size_t)RROWS * 4;
  int*   pos  = (int*)p;   p += (size_t)TOKENS * 2 * 4;
  int*   sel  = (int*)p;   p += (size_t)TOKENS * 2 * 4;
  float* wsel = (float*)p; p += (size_t)TOKENS * 2 * 4;
  int* cnt    = (int*)p;   p += 32 * 4;
  int* off    = (int*)p;   p += 32 * 4;
  // eout aliases w1t (dead after gemm1; same size; rewritten each replay)
  unsigned short* eout = w1t;

  const int nb1 = E_ * (D_ / 64) * (H_ / 64);
  const int nb2 = E_ * (H_ / 64) * (D_ / 64);
  prologue_kernel<<<TOKENS / 4 + nb1 + nb2, 256, 0, stream>>>(
      x, gate, xb, sel, wsel, W1, w1t, W2, w2t);
  route_kernel<<<1, 1024, 0, stream>>>(sel, cnt, off, tok, pos);
  gemm1_kernel<<<E_ * 16 * 8, 512, 0, stream>>>(xb, w1t, b1, hbuf, tok, cnt, off);
  gemm2_kernel<<<E_ * 16 * 4, 512, 0, stream>>>(hbuf, w2t, eout, cnt, off);
  combine_kernel<<<TOKENS / 4, 256, 0, stream>>>(eout, b2, sel, wsel, pos, out);
}